// Round 8
// baseline (629.312 us; speedup 1.0000x reference)
//
#include <hip/hip_runtime.h>
#include <cstdint>

typedef unsigned short u16;
typedef unsigned int u32;
typedef __attribute__((ext_vector_type(4))) float f32x4;
typedef __attribute__((ext_vector_type(8))) __bf16 bf16x8;
typedef __attribute__((ext_vector_type(8))) unsigned short u16x8;
typedef __attribute__((ext_vector_type(4))) unsigned int u32x4;

#define S_LEN 2048
#define BATCH 2
#define NQH 32
#define NKVH 8
#define HD 96
#define EMB 3072
#define QKVN 4608
#define KOFF 3072
#define VOFF 3840
#define KSP 104
#define CL2 0.14724601498759837f  // (1/sqrt(96)) * log2(e)

__device__ __forceinline__ u16 f2b(float f) {
    u32 u = __float_as_uint(f);
    u32 r = (u + 0x7fffu + ((u >> 16) & 1u)) >> 16;
    return (u16)r;
}
__device__ __forceinline__ float b2f(u16 h) { return __uint_as_float(((u32)h) << 16); }
__device__ __forceinline__ u32 cvtpk(float lo, float hi) {
    u32 r;
    asm("v_cvt_pk_bf16_f32 %0, %1, %2" : "=v"(r) : "v"(lo), "v"(hi));
    return r;
}

// ---------------- fp32 -> bf16 bulk convert ----------------
__global__ __launch_bounds__(256) void conv_f2b(const float* __restrict__ in,
                                                u16* __restrict__ outp, int n8) {
    const int i = blockIdx.x * 256 + threadIdx.x;
    if (i >= n8) return;
    const f32x4* q = (const f32x4*)(in + (size_t)i * 8);
    const f32x4 a = q[0], b = q[1];
    u16x8 t;
#pragma unroll
    for (int j = 0; j < 4; ++j) {
        t[j] = f2b(a[j]);
        t[j + 4] = f2b(b[j]);
    }
    *(u16x8*)(outp + (size_t)i * 8) = t;
}

// ---------------- async global->LDS helper ----------------
typedef __attribute__((address_space(1))) const uint32_t gas_u32;
typedef __attribute__((address_space(3))) uint32_t las_u32;
__device__ __forceinline__ void gld_lds16(const u16* g, u16* l) {
    __builtin_amdgcn_global_load_lds((gas_u32*)g, (las_u32*)l, 16, 0, 0);
}

#define WAITV8 asm volatile("s_waitcnt vmcnt(8)" ::: "memory")
#define LGKM0 asm volatile("s_waitcnt lgkmcnt(0)" ::: "memory")
#define BARRIERM asm volatile("s_barrier" ::: "memory")
#define SCHEDB __builtin_amdgcn_sched_barrier(0)

// ============ 256x256 GEMM, BK=32, 4-deep LDS ring (unchanged from R7) ============
__device__ __forceinline__ void stage32(const u16* __restrict__ G, int ldg, int k0,
                                        u16* buf, int tid) {
#pragma unroll
    for (int L = 0; L < 2; ++L) {
        const int c = L * 512 + tid;
        const int r = c >> 2;
        const int sg = (c & 3) ^ ((r >> 1) & 3);
        const u16* src = G + (size_t)r * ldg + k0 + sg * 8;
        u16* dst = buf + (L * 512 + (tid & 448)) * 8;
        gld_lds16(src, dst);
    }
}

__device__ __forceinline__ bf16x8 frag32(const u16* buf, int row, int s) {
    const int sg = s ^ ((row >> 1) & 3);
    return *(const bf16x8*)(buf + row * 32 + sg * 8);
}

template <bool OUTF32>
__global__ __launch_bounds__(512, 1) void gemm_bt32(const u16* __restrict__ Ap,
                                                    const u16* __restrict__ Bp,
                                                    void* __restrict__ Cp,
                                                    int M, int N, int K, int ldc) {
    __shared__ __align__(16) u16 S[65536];
    const int tid = threadIdx.x;
    const int lane = tid & 63;
    const int lrow = lane & 15, lhi = lane >> 4;
    const int wid = tid >> 6;
    const int wr = wid >> 2, wc = wid & 3;
    const int bm = blockIdx.y * 256, bn = blockIdx.x * 256;
    const u16* Ab = Ap + (size_t)bm * K;
    const u16* Bb = Bp + (size_t)bn * K;

    f32x4 acc[8][4] = {};
    const int nt = K >> 5;
    const int arow0 = wr * 128 + lrow;
    const int brow0 = wc * 64 + lrow;

#pragma unroll
    for (int t = 0; t < 3; ++t) {
        stage32(Ab, K, t * 32, S + t * 16384, tid);
        stage32(Bb, K, t * 32, S + t * 16384 + 8192, tid);
    }

    for (int t = 0; t < nt; ++t) {
        const u16* Ac = S + (t & 3) * 16384;
        const u16* Bc = Ac + 8192;
        u16* Sn = S + ((t + 3) & 3) * 16384;
        const int kn = (t + 3 < nt) ? (t + 3) * 32 : 0;

        WAITV8;
        BARRIERM;

        bf16x8 af[8], bfr[2];
#pragma unroll
        for (int mi = 0; mi < 8; ++mi) af[mi] = frag32(Ac, arow0 + mi * 16, lhi);
#pragma unroll
        for (int ni = 0; ni < 2; ++ni) bfr[ni] = frag32(Bc, brow0 + ni * 16, lhi);
        stage32(Ab, K, kn, Sn, tid);
        LGKM0;
        SCHEDB;
        __builtin_amdgcn_s_setprio(1);
#pragma unroll
        for (int mi = 0; mi < 8; ++mi)
#pragma unroll
            for (int ni = 0; ni < 2; ++ni)
                acc[mi][ni] = __builtin_amdgcn_mfma_f32_16x16x32_bf16(af[mi], bfr[ni],
                                                                      acc[mi][ni], 0, 0, 0);
        __builtin_amdgcn_s_setprio(0);

#pragma unroll
        for (int ni = 0; ni < 2; ++ni) bfr[ni] = frag32(Bc, brow0 + (ni + 2) * 16, lhi);
        stage32(Bb, K, kn, Sn + 8192, tid);
        LGKM0;
        SCHEDB;
        __builtin_amdgcn_s_setprio(1);
#pragma unroll
        for (int mi = 0; mi < 8; ++mi)
#pragma unroll
            for (int ni = 0; ni < 2; ++ni)
                acc[mi][ni + 2] = __builtin_amdgcn_mfma_f32_16x16x32_bf16(af[mi], bfr[ni],
                                                                          acc[mi][ni + 2], 0, 0, 0);
        __builtin_amdgcn_s_setprio(0);
    }

    const int orow = bm + wr * 128 + lhi * 4;
    const int ocol = bn + wc * 64 + lrow;
#pragma unroll
    for (int mi = 0; mi < 8; ++mi)
#pragma unroll
        for (int ni = 0; ni < 4; ++ni)
#pragma unroll
            for (int r = 0; r < 4; ++r) {
                const size_t idx = (size_t)(orow + mi * 16 + r) * ldc + ocol + ni * 16;
                if constexpr (OUTF32)
                    ((float*)Cp)[idx] = acc[mi][ni][r];
                else
                    ((u16*)Cp)[idx] = f2b(acc[mi][ni][r]);
            }
}

// ---------------- RoPE in-place, vectorized ----------------
__global__ __launch_bounds__(256) void gqa_rope8(u16* __restrict__ qkv,
                                                 const int* __restrict__ positions) {
    const int i = blockIdx.x * 256 + threadIdx.x;
    const int pc = i % 6;
    int t = i / 6;
    const int head = t % (NQH + NKVH);
    const int bs = t / (NQH + NKVH);
    const int pos = positions[bs & (S_LEN - 1)];
    const size_t base = (size_t)bs * QKVN +
                        (head < NQH ? head * HD : KOFF + (head - NQH) * HD) + pc * 8;
    const u16x8 a = *(const u16x8*)(qkv + base);
    const u16x8 b = *(const u16x8*)(qkv + base + 48);
    u16x8 ra, rb;
#pragma unroll
    for (int jj = 0; jj < 8; ++jj) {
        const int pair = pc * 8 + jj;
        const float invf = __expf(-(float)(2 * pair) * (1.0f / 96.0f) * 9.210340371976184f);
        const float ang = (float)pos * invf;
        float sn, cs;
        __sincosf(ang, &sn, &cs);
        const float t1 = b2f(a[jj]), t2 = b2f(b[jj]);
        ra[jj] = f2b(t1 * cs - t2 * sn);
        rb[jj] = f2b(t2 * cs + t1 * sn);
    }
    *(u16x8*)(qkv + base) = ra;
    *(u16x8*)(qkv + base + 48) = rb;
}

// ---------------- Flash GQA v6: KV-split for the 16 largest q-tiles ----------------
// Grid 1280: bx<768 unsplit band qt32=47-(bx>>4) (max 24 tiles);
//            bx>=768: qt32=63-(s>>5) in [48,64), split bit sp=r&1 -> KV half [0,half)/[half,last].
// Split parts write unnormalized f32 O^T + (m,l) partials to `part` (in d_out);
// attn_merge combines exactly. Unsplit path identical to R7.
__global__ __launch_bounds__(256) void gqa_attn6(const u16* __restrict__ qkv,
                                                 u16* __restrict__ out,
                                                 float* __restrict__ part) {
    __shared__ __align__(16) u16 Ks[64 * KSP];
    __shared__ __align__(16) u16 Vtmp[64 * 96];
    __shared__ __align__(16) u16 Vt[96 * 72];

    const int tid = threadIdx.x;
    const int wave = tid >> 6, lane = tid & 63;
    const int lrow = lane & 15, lhi = lane >> 4;
    const int bx = blockIdx.x;

    int qt32, kvh, bb, sp, kb_lo, kb_hi;
    bool dosplit;
    if (bx < 768) {
        qt32 = 47 - (bx >> 4);
        kvh = (bx >> 1) & 7;
        bb = bx & 1;
        sp = 0;
        kb_lo = 0;
        kb_hi = (qt32 * 32 + 31) >> 6;
        dosplit = false;
    } else {
        const int s = bx - 768;
        qt32 = 63 - (s >> 5);
        const int r = s & 31;
        kvh = (r >> 2) & 7;
        bb = (r >> 1) & 1;
        sp = r & 1;
        const int kb_last = (qt32 * 32 + 31) >> 6;
        const int half = (kb_last + 1) >> 1;
        kb_lo = sp ? half : 0;
        kb_hi = sp ? kb_last : half - 1;
        dosplit = true;
    }
    const int kb_abs_last = (qt32 * 32 + 31) >> 6;
    const int qh = kvh * 4 + wave;
    const int srow0 = bb * S_LEN + qt32 * 32;

    bf16x8 bq[2][3];
#pragma unroll
    for (int qt = 0; qt < 2; ++qt)
#pragma unroll
        for (int kd = 0; kd < 3; ++kd)
            bq[qt][kd] = *(const bf16x8*)(qkv + (size_t)(srow0 + qt * 16 + lrow) * QKVN +
                                          qh * 96 + kd * 32 + lhi * 8);

    float m_s[2] = {-3e38f, -3e38f}, l_s[2] = {0.0f, 0.0f};
    f32x4 oacc[6][2] = {};

    const int s0 = lrow + ((lane & 16) ? 32 : 0);
    const int s1 = s0 + 16;
    const bool khi = (lane & 32) != 0;

    const size_t kvrow0 = (size_t)(bb * S_LEN) * QKVN;
    u16x8 kreg[3], vreg[3];

    {  // prologue: stage tile kb_lo
        const size_t kbase = kvrow0 + (size_t)(kb_lo * 64) * QKVN + KOFF + (size_t)kvh * 96;
        const size_t vbase = kvrow0 + (size_t)(kb_lo * 64) * QKVN + VOFF + (size_t)kvh * 96;
#pragma unroll
        for (int i = 0; i < 3; ++i) {
            const int u = tid + 256 * i;
            const int so = (u % 12) * 8, sr = u / 12;
            kreg[i] = *(const u16x8*)(qkv + kbase + (size_t)sr * QKVN + so);
            vreg[i] = *(const u16x8*)(qkv + vbase + (size_t)sr * QKVN + so);
        }
#pragma unroll
        for (int i = 0; i < 3; ++i) {
            const int u = tid + 256 * i;
            const int so = (u % 12) * 8, sr = u / 12;
            *(u16x8*)(Ks + sr * KSP + so) = kreg[i];
            *(u16x8*)(Vtmp + sr * 96 + so) = vreg[i];
        }
        __syncthreads();
#pragma unroll
        for (int i = 0; i < 3; ++i) {
            const int u = tid + 256 * i;
            const int td = u % 96, ts8 = u / 96;
            u16x8 c;
#pragma unroll
            for (int j = 0; j < 8; ++j) c[j] = Vtmp[(ts8 * 8 + j) * 96 + td];
            *(u16x8*)(Vt + td * 72 + ts8 * 8) = c;
        }
    }

    for (int kb = kb_lo; kb <= kb_hi; ++kb) {
        if (kb < kb_hi) {  // T14: prefetch next tile's K/V into regs
            const size_t kbase2 = kvrow0 + (size_t)((kb + 1) * 64) * QKVN + KOFF + kvh * 96;
            const size_t vbase2 = kvrow0 + (size_t)((kb + 1) * 64) * QKVN + VOFF + kvh * 96;
#pragma unroll
            for (int i = 0; i < 3; ++i) {
                const int u = tid + 256 * i;
                const int so = (u % 12) * 8, sr = u / 12;
                kreg[i] = *(const u16x8*)(qkv + kbase2 + (size_t)sr * QKVN + so);
                vreg[i] = *(const u16x8*)(qkv + vbase2 + (size_t)sr * QKVN + so);
            }
        }
        __syncthreads();

        bf16x8 ka[4][3];
#pragma unroll
        for (int kt = 0; kt < 4; ++kt)
#pragma unroll
            for (int kd = 0; kd < 3; ++kd)
                ka[kt][kd] = *(const bf16x8*)(Ks + (kt * 16 + lrow) * KSP + kd * 32 + lhi * 8);

        const int qoff = qt32 * 32 - kb * 64;
        const bool lastkb = (kb == kb_abs_last);
        u32 bp[2][2][4];

#pragma unroll
        for (int qt = 0; qt < 2; ++qt) {
            const int qrelmax = qoff + qt * 16 + 15;
            f32x4 sacc[4] = {};
#pragma unroll
            for (int kt = 0; kt < 4; ++kt) {
                if (lastkb && kt * 16 > qrelmax) continue;
#pragma unroll
                for (int kd = 0; kd < 3; ++kd)
                    sacc[kt] = __builtin_amdgcn_mfma_f32_16x16x32_bf16(ka[kt][kd], bq[qt][kd],
                                                                       sacc[kt], 0, 0, 0);
            }
            float p[4][4];
            float mx = -3e38f;
            if (lastkb) {
                const int qrel = qoff + qt * 16 + lrow;
#pragma unroll
                for (int kt = 0; kt < 4; ++kt)
#pragma unroll
                    for (int r = 0; r < 4; ++r) {
                        const bool live = (kt * 16 + lhi * 4 + r) <= qrel;
                        const float s = live ? sacc[kt][r] : -3e38f;
                        p[kt][r] = s;
                        mx = fmaxf(mx, s);
                    }
            } else {
#pragma unroll
                for (int kt = 0; kt < 4; ++kt)
#pragma unroll
                    for (int r = 0; r < 4; ++r) {
                        p[kt][r] = sacc[kt][r];
                        mx = fmaxf(mx, sacc[kt][r]);
                    }
            }
            mx = fmaxf(mx, __shfl_xor(mx, 16));
            mx = fmaxf(mx, __shfl_xor(mx, 32));
            float mn = m_s[qt];
            if (!__all(mx - mn <= 20.0f)) {
                const float mnew = fmaxf(mn, mx);
                const float alpha = exp2f((mn - mnew) * CL2);
                m_s[qt] = mnew;
                mn = mnew;
                l_s[qt] *= alpha;
#pragma unroll
                for (int dt = 0; dt < 6; ++dt)
#pragma unroll
                    for (int r = 0; r < 4; ++r) oacc[dt][qt][r] *= alpha;
            }
            float rs = 0.0f;
#pragma unroll
            for (int kt = 0; kt < 4; ++kt)
#pragma unroll
                for (int r = 0; r < 4; ++r) {
                    const float pv = exp2f((p[kt][r] - mn) * CL2);
                    p[kt][r] = pv;
                    rs += pv;
                }
            rs += __shfl_xor(rs, 16);
            rs += __shfl_xor(rs, 32);
            l_s[qt] += rs;
            u32 pk[4][2];
#pragma unroll
            for (int kt = 0; kt < 4; ++kt) {
                pk[kt][0] = cvtpk(p[kt][0], p[kt][1]);
                pk[kt][1] = cvtpk(p[kt][2], p[kt][3]);
            }
#pragma unroll
            for (int kk = 0; kk < 2; ++kk) {
                const u32 a0 = (u32)__shfl((int)pk[kk * 2][0], s0, 64);
                const u32 b0 = (u32)__shfl((int)pk[kk * 2 + 1][0], s0, 64);
                const u32 a1 = (u32)__shfl((int)pk[kk * 2][1], s0, 64);
                const u32 b1 = (u32)__shfl((int)pk[kk * 2 + 1][1], s0, 64);
                const u32 a2 = (u32)__shfl((int)pk[kk * 2][0], s1, 64);
                const u32 b2 = (u32)__shfl((int)pk[kk * 2 + 1][0], s1, 64);
                const u32 a3 = (u32)__shfl((int)pk[kk * 2][1], s1, 64);
                const u32 b3 = (u32)__shfl((int)pk[kk * 2 + 1][1], s1, 64);
                bp[qt][kk][0] = khi ? b0 : a0;
                bp[qt][kk][1] = khi ? b1 : a1;
                bp[qt][kk][2] = khi ? b2 : a2;
                bp[qt][kk][3] = khi ? b3 : a3;
            }
        }

#pragma unroll
        for (int dt = 0; dt < 6; ++dt) {
            bf16x8 va[2];
#pragma unroll
            for (int kk = 0; kk < 2; ++kk)
                va[kk] = *(const bf16x8*)(Vt + (dt * 16 + lrow) * 72 + kk * 32 + lhi * 8);
#pragma unroll
            for (int qt = 0; qt < 2; ++qt)
#pragma unroll
                for (int kk = 0; kk < 2; ++kk) {
                    const u32x4 bv = {bp[qt][kk][0], bp[qt][kk][1], bp[qt][kk][2], bp[qt][kk][3]};
                    oacc[dt][qt] = __builtin_amdgcn_mfma_f32_16x16x32_bf16(
                        va[kk], __builtin_bit_cast(bf16x8, bv), oacc[dt][qt], 0, 0, 0);
                }
        }

        __syncthreads();
        if (kb < kb_hi) {
#pragma unroll
            for (int i = 0; i < 3; ++i) {
                const int u = tid + 256 * i;
                const int so = (u % 12) * 8, sr = u / 12;
                *(u16x8*)(Ks + sr * KSP + so) = kreg[i];
                *(u16x8*)(Vtmp + sr * 96 + so) = vreg[i];
            }
            __syncthreads();
#pragma unroll
            for (int i = 0; i < 3; ++i) {
                const int u = tid + 256 * i;
                const int td = u % 96, ts8 = u / 96;
                u16x8 c;
#pragma unroll
                for (int j = 0; j < 8; ++j) c[j] = Vtmp[(ts8 * 8 + j) * 96 + td];
                *(u16x8*)(Vt + td * 72 + ts8 * 8) = c;
            }
        }
    }

    if (!dosplit) {
        const size_t obase = (size_t)srow0 * EMB + qh * 96;
#pragma unroll
        for (int qt = 0; qt < 2; ++qt) {
            const float inv = 1.0f / l_s[qt];
            const size_t rbase = obase + (size_t)(qt * 16 + lrow) * EMB;
#pragma unroll
            for (int dt = 0; dt < 6; ++dt)
#pragma unroll
                for (int rp = 0; rp < 2; ++rp) {
                    const u32 pair =
                        cvtpk(oacc[dt][qt][2 * rp] * inv, oacc[dt][qt][2 * rp + 1] * inv);
                    *(u32*)(out + rbase + dt * 16 + lhi * 4 + 2 * rp) = pair;
                }
        }
    } else {
        // f32 partial: O unnormalized + (m,l). prow = bb*512 + (qt32-48)*32 + qrow.
        float* opart = part + (size_t)sp * 1024 * EMB;
        float* ml = part + (size_t)2 * 1024 * EMB;
        const int prow_b = bb * 512 + (qt32 - 48) * 32;
#pragma unroll
        for (int qt = 0; qt < 2; ++qt) {
            const int prow = prow_b + qt * 16 + lrow;
            float* rb = opart + (size_t)prow * EMB + qh * 96;
#pragma unroll
            for (int dt = 0; dt < 6; ++dt)
                *(f32x4*)(rb + dt * 16 + lhi * 4) = oacc[dt][qt];
            if (lhi == 0) {
                float* mlp = ml + ((size_t)(sp * 1024 + prow) * 32 + qh) * 2;
                mlp[0] = m_s[qt];
                mlp[1] = l_s[qt];
            }
        }
    }
}

// ---------------- merge the two KV-split partials (exact math) ----------------
__global__ __launch_bounds__(256) void attn_merge(const float* __restrict__ part,
                                                  u16* __restrict__ out) {
    const int j = blockIdx.x * 256 + threadIdx.x;  // 1024*32*12 = 393216
    const int oct = j % 12;
    const int t = j / 12;
    const int qh = t & 31;
    const int prow = t >> 5;  // [0,1024)
    const float* ml = part + (size_t)2 * 1024 * EMB;
    const float* m0p = ml + ((size_t)prow * 32 + qh) * 2;
    const float* m1p = ml + ((size_t)(1024 + prow) * 32 + qh) * 2;
    const float m0 = m0p[0], l0 = m0p[1], m1 = m1p[0], l1 = m1p[1];
    const float M = fmaxf(m0, m1);
    const float e0 = exp2f((m0 - M) * CL2);
    const float e1 = exp2f((m1 - M) * CL2);
    const float inv = 1.0f / (e0 * l0 + e1 * l1);
    const float* o0 = part + (size_t)prow * EMB + qh * 96 + oct * 8;
    const float* o1 = o0 + (size_t)1024 * EMB;
    const int bb = prow >> 9;
    const int qt32 = 48 + ((prow & 511) >> 5);
    const int qrow = prow & 31;
    const int srow = bb * S_LEN + qt32 * 32 + qrow;
    u16* dst = out + (size_t)srow * EMB + qh * 96 + oct * 8;
    u32 w[4];
#pragma unroll
    for (int pr = 0; pr < 4; ++pr) {
        const float a = (e0 * o0[2 * pr] + e1 * o1[2 * pr]) * inv;
        const float b = (e0 * o0[2 * pr + 1] + e1 * o1[2 * pr + 1]) * inv;
        w[pr] = cvtpk(a, b);
    }
    *(u32x4*)dst = {w[0], w[1], w[2], w[3]};
}

extern "C" void kernel_launch(void* const* d_in, const int* in_sizes, int n_in,
                              void* d_out, int out_size, void* d_ws, size_t ws_size,
                              hipStream_t stream) {
    const float* x = (const float*)d_in[0];
    const int* positions = (const int*)d_in[1];
    const float* W_qkv = (const float*)d_in[3];
    const float* W_o = (const float*)d_in[4];
    float* out = (float*)d_out;

    const int M = BATCH * S_LEN;               // 4096
    const size_t QKV_E = (size_t)M * QKVN;     // 18,874,368
    const size_t X_E = (size_t)M * EMB;
    const size_t WQKV_E = (size_t)QKVN * EMB;  // 28.3 MB bf16
    const size_t WO_E = (size_t)EMB * EMB;

    // ws (62.9 MB): qkv [0,QKV_E) ; scratch [QKV_E,+ATT_E) = xb -> attn_out
    // d_out (50.3 MB): wqkvb (dead after GEMM1) -> attn f32 partials (25.7 MB)
    u16* qkv = (u16*)d_ws;
    u16* scratch = qkv + QKV_E;
    u16* xb = scratch;
    u16* wqkvb = (u16*)d_out;
    float* part = (float*)d_out;
    u16* wob = (u16*)d_ws;  // overwrites qkv head after attn

    conv_f2b<<<(int)(X_E / 8 / 256), 256, 0, stream>>>(x, xb, (int)(X_E / 8));
    conv_f2b<<<(int)(WQKV_E / 8 / 256), 256, 0, stream>>>(W_qkv, wqkvb, (int)(WQKV_E / 8));
    gemm_bt32<false>
        <<<dim3(QKVN / 256, M / 256), 512, 0, stream>>>(xb, wqkvb, qkv, M, QKVN, EMB, QKVN);
    gqa_rope8<<<(BATCH * S_LEN * (NQH + NKVH) * 6) / 256, 256, 0, stream>>>(qkv, positions);
    gqa_attn6<<<dim3(1280), 256, 0, stream>>>(qkv, scratch, part);  // scratch: xb dead
    attn_merge<<<dim3(1536), 256, 0, stream>>>(part, scratch);
    conv_f2b<<<(int)(WO_E / 8 / 256), 256, 0, stream>>>(W_o, wob, (int)(WO_E / 8));
    gemm_bt32<true>
        <<<dim3(EMB / 256, M / 256), 512, 0, stream>>>(scratch, wob, out, M, EMB, EMB, EMB);
}